// Round 15
// baseline (121.032 us; speedup 1.0000x reference)
//
#include <hip/hip_runtime.h>
#include <hip/hip_bf16.h>

typedef __attribute__((ext_vector_type(4))) float f32x4;
typedef __attribute__((ext_vector_type(16))) float f32x16;
typedef __attribute__((ext_vector_type(8))) short bf16x8;

#define NH 8
#define HD 64
#define WSZ 128
#define DM 512

typedef __attribute__((address_space(3))) void lds_t;
typedef const __attribute__((address_space(1))) void gbl_t;

__device__ __forceinline__ unsigned int pk2bf(float lo, float hi) {
    union { __hip_bfloat162 h; unsigned int u; } r;
    r.h = __float22bfloat162_rn(make_float2(lo, hi));
    return r.u;
}

__device__ __forceinline__ bf16x8 pack8(f32x4 a, f32x4 b) {
    union { unsigned int u[4]; bf16x8 v; } r;
    r.u[0] = pk2bf(a[0], a[1]);
    r.u[1] = pk2bf(a[2], a[3]);
    r.u[2] = pk2bf(b[0], b[1]);
    r.u[3] = pk2bf(b[2], b[3]);
    return r.v;
}

// TWO-TILE PIPELINE: each block processes tiles (2b, 2b+1). K/V staged fp32
// via global_load_lds into DOUBLE buffers (128 KB LDS, 1 block/CU): tile1's
// 64KB burst is issued right after the barrier that publishes tile0, so it
// is in flight during ALL of tile0's compute+store -> continuous per-CU load
// pressure (the r14 post-mortem's surviving hypothesis: bursty demand, not a
// bandwidth ceiling, pins us at ~4.6 TB/s delivered).
// Compute body identical to r14 (passing): swapped QK^T 32x32x16 -> S^T,
// lane-local softmax, P via cvt_pk+permlane32_swap, V B-frags via 8x
// ds_read_b32 (conflict-free, 0 measured conflicts in r14).
__global__ __launch_bounds__(256, 1) void wattn_kernel(
    const float* __restrict__ q1, const float* __restrict__ k1,
    const float* __restrict__ v1, float* __restrict__ o1, int nw1,
    const float* __restrict__ q2, const float* __restrict__ k2,
    const float* __restrict__ v2, float* __restrict__ o2, int nw2,
    int nt1)
{
    // [buf][128*64] fp32. Kl granule-swizzled (gs^(row&15)); Vl linear.
    __shared__ __align__(16) float Kl[2][128 * 64];
    __shared__ __align__(16) float Vl[2][128 * 64];

    const int t = threadIdx.x;
    const int lane = t & 63;
    const int wid = t >> 6;
    const int hi = lane >> 5;   // 0..1
    const int c = lane & 31;    // 0..31
    const int qbase = wid * 32;

    auto tile_ptrs = [&](int ti, const float*& Qp, const float*& Kp,
                         const float*& Vp, float*& Op) {
        const float *q, *k, *v; float* o; int nw; int x = ti;
        if (x < nt1) { q = q1; k = k1; v = v1; o = o1; nw = nw1; }
        else { x -= nt1; q = q2; k = k2; v = v2; o = o2; nw = nw2; }
        const int h = x & (NH - 1);
        const int w = (x >> 3) % nw;
        const int b = (x >> 3) / nw;
        const size_t row0 = ((size_t)b * nw + w) * WSZ;
        Qp = q + row0 * DM + h * HD;
        Kp = k + row0 * DM + h * HD;
        Vp = v + row0 * DM + h * HD;
        Op = o + row0 * DM + h * HD;
    };

    // 16 global_load_lds per wave: fire-and-forget, zero VGPR, unsinkable.
    auto burst = [&](int buf, const float* Kp_, const float* Vp_) {
#pragma unroll
        for (int ii = 0; ii < 8; ++ii) {
            const int idx = wid * 8 + ii;
            const int row = idx * 4 + (lane >> 4);
            const int gs = lane & 15;
            __builtin_amdgcn_global_load_lds(
                (gbl_t*)(Kp_ + (size_t)row * DM + ((gs ^ (row & 15)) << 2)),
                (lds_t*)((char*)&Kl[buf][0] + idx * 1024), 16, 0, 0);
            __builtin_amdgcn_global_load_lds(
                (gbl_t*)(Vp_ + (size_t)row * DM + (gs << 2)),
                (lds_t*)((char*)&Vl[buf][0] + idx * 1024), 16, 0, 0);
        }
    };

    auto loadq = [&](const float* Qp_, bf16x8 (&qf)[4]) {
#pragma unroll
        for (int ks = 0; ks < 4; ++ks) {
            const float* src = Qp_ + (size_t)(qbase + c) * DM + ks * 16 + hi * 8;
            qf[ks] = pack8(*reinterpret_cast<const f32x4*>(src),
                           *reinterpret_cast<const f32x4*>(src + 4));
        }
    };

    const float CEXP = 0.125f * 1.4426950408889634f;

    auto compute_tile = [&](const float* KB, const float* VB,
                            bf16x8 (&qf)[4], float* OpS) {
        // S^T = K Q^T : D col=c (q), row k = mf*32+(reg&3)+8*(reg>>2)+4*hi
        f32x16 acc[4] = {};
#pragma unroll
        for (int ks = 0; ks < 4; ++ks) {
#pragma unroll
            for (int mf = 0; mf < 4; ++mf) {
                const int row = mf * 32 + c;
                const int r15 = c & 15;
                const int g0 = ks * 4 + hi * 2;
                f32x4 a = *reinterpret_cast<const f32x4*>(&KB[row * 64 + ((g0 ^ r15) << 2)]);
                f32x4 bq = *reinterpret_cast<const f32x4*>(&KB[row * 64 + (((g0 + 1) ^ r15) << 2)]);
                acc[mf] = __builtin_amdgcn_mfma_f32_32x32x16_bf16(pack8(a, bq), qf[ks], acc[mf], 0, 0, 0);
            }
        }

        // softmax over k: lane-local, tree-reduced, one cross-half shfl
        float mxa = fmaxf(acc[0][0], acc[1][0]);
        float mxb = fmaxf(acc[2][0], acc[3][0]);
#pragma unroll
        for (int e = 1; e < 16; ++e) {
            mxa = fmaxf(mxa, fmaxf(acc[0][e], acc[1][e]));
            mxb = fmaxf(mxb, fmaxf(acc[2][e], acc[3][e]));
        }
        float mx = fmaxf(mxa, mxb);
        mx = fmaxf(mx, __shfl_xor(mx, 32));
        const float mxc = mx * CEXP;
        float s0 = 0.f, s1 = 0.f, s2 = 0.f, s3 = 0.f;
#pragma unroll
        for (int e = 0; e < 16; ++e) {
            float p0 = exp2f(acc[0][e] * CEXP - mxc);
            float p1 = exp2f(acc[1][e] * CEXP - mxc);
            float p2 = exp2f(acc[2][e] * CEXP - mxc);
            float p3 = exp2f(acc[3][e] * CEXP - mxc);
            acc[0][e] = p0; acc[1][e] = p1; acc[2][e] = p2; acc[3][e] = p3;
            s0 += p0; s1 += p1; s2 += p2; s3 += p3;
        }
        float sum = (s0 + s1) + (s2 + s3);
        sum += __shfl_xor(sum, 32);
        const float rinv = 1.0f / sum;

        // O = P V : pack P + permlane32_swap -> A-frag; V B-frag = 8x b32 + cvt
        f32x16 oacc[2] = {};
#pragma unroll
        for (int f = 0; f < 4; ++f) {
#pragma unroll
            for (int p = 0; p < 2; ++p) {
                const int kb2 = f * 2 + p;
                unsigned int U0 = pk2bf(acc[f][8 * p + 0], acc[f][8 * p + 1]);
                unsigned int U1 = pk2bf(acc[f][8 * p + 2], acc[f][8 * p + 3]);
                unsigned int U2 = pk2bf(acc[f][8 * p + 4], acc[f][8 * p + 5]);
                unsigned int U3 = pk2bf(acc[f][8 * p + 6], acc[f][8 * p + 7]);
                asm volatile("v_permlane32_swap_b32 %0, %1" : "+v"(U0), "+v"(U2));
                asm volatile("v_permlane32_swap_b32 %0, %1" : "+v"(U1), "+v"(U3));
                union { unsigned int u[4]; bf16x8 v; } A;
                A.u[0] = U0; A.u[1] = U1; A.u[2] = U2; A.u[3] = U3;
                const int k0 = kb2 * 16 + hi * 8;
#pragma unroll
                for (int nf = 0; nf < 2; ++nf) {
                    const float* vb = &VB[k0 * 64 + nf * 32 + c];
                    union { unsigned int u[4]; bf16x8 v; } V8;
                    V8.u[0] = pk2bf(vb[0 * 64], vb[1 * 64]);
                    V8.u[1] = pk2bf(vb[2 * 64], vb[3 * 64]);
                    V8.u[2] = pk2bf(vb[4 * 64], vb[5 * 64]);
                    V8.u[3] = pk2bf(vb[6 * 64], vb[7 * 64]);
                    oacc[nf] = __builtin_amdgcn_mfma_f32_32x32x16_bf16(A.v, V8.v, oacc[nf], 0, 0, 0);
                }
            }
        }

        // store O with deferred 1/rowsum broadcast from q-owner lanes
#pragma unroll
        for (int reg = 0; reg < 16; ++reg) {
            const int qr = (reg & 3) + 8 * (reg >> 2) + 4 * hi;
            const float rv = __shfl(rinv, qr);
#pragma unroll
            for (int nf = 0; nf < 2; ++nf) {
                OpS[(size_t)(qbase + qr) * DM + nf * 32 + c] = oacc[nf][reg] * rv;
            }
        }
    };

    // ================= two-tile pipeline =================
    const int t0 = blockIdx.x * 2;
    const float *Qp, *Kp, *Vp; float* Op;

    tile_ptrs(t0, Qp, Kp, Vp, Op);
    burst(0, Kp, Vp);                 // tile0 K/V -> buf0
    bf16x8 qf0[4];
    loadq(Qp, qf0);                   // Q0 -> regs (cvt anchors the loads)
    float* Op0 = Op;

    tile_ptrs(t0 + 1, Qp, Kp, Vp, Op);

    __syncthreads();                  // vmcnt(0) drain: tile0 staged

    burst(1, Kp, Vp);                 // tile1 K/V -> buf1, flies under compute0
    bf16x8 qf1[4];
    loadq(Qp, qf1);                   // Q1 early: latency rides under compute0

    compute_tile(&Kl[0][0], &Vl[0][0], qf0, Op0);

    __syncthreads();                  // vmcnt(0) drain: tile1 staged

    compute_tile(&Kl[1][0], &Vl[1][0], qf1, Op);
}

extern "C" void kernel_launch(void* const* d_in, const int* in_sizes, int n_in,
                              void* d_out, int out_size, void* d_ws, size_t ws_size,
                              hipStream_t stream) {
    const float* q1 = (const float*)d_in[0];
    const float* k1 = (const float*)d_in[1];
    const float* v1 = (const float*)d_in[2];
    const float* q2 = (const float*)d_in[3];
    const float* k2 = (const float*)d_in[4];
    const float* v2 = (const float*)d_in[5];

    const int B = 8;
    const int nw1 = in_sizes[0] / (B * DM * WSZ);   // 32
    const int nw2 = in_sizes[3] / (B * DM * WSZ);   // 16

    float* o1 = (float*)d_out;
    float* o2 = o1 + (size_t)in_sizes[0];

    const int nt1 = B * nw1 * NH;                   // 2048 tiles (set 1)
    const int nt2 = B * nw2 * NH;                   // 1024 tiles (set 2)
    const int nblk = (nt1 + nt2) / 2;               // 1536 blocks x 2 tiles

    wattn_kernel<<<dim3(nblk), dim3(256), 0, stream>>>(
        q1, k1, v1, o1, nw1, q2, k2, v2, o2, nw2, nt1);
}